// Round 1
// baseline (541.959 us; speedup 1.0000x reference)
//
#include <hip/hip_runtime.h>
#include <hip/hip_bf16.h>

#define N_FEAT 3072
#define LATENT 128
#define LOG2PI 1.8378770664093453f

typedef __attribute__((ext_vector_type(8))) short short8;
typedef __attribute__((ext_vector_type(4))) float f32x4;

__device__ __forceinline__ unsigned short f2bf(float x) {
  unsigned int u = __float_as_uint(x);
  u += 0x7FFFu + ((u >> 16) & 1u);
  return (unsigned short)(u >> 16);
}

// ---------------------------------------------------------------------------
// Kernel A: M = W^T W + sigma^2 I   (M is 128x128 fp32 in ws)
// block i computes row i of M; thread j computes M[i][j].
// ---------------------------------------------------------------------------
__global__ __launch_bounds__(128) void k_gram(const float* __restrict__ W,
                                              const float* __restrict__ log_var,
                                              float* __restrict__ M) {
  int i = blockIdx.x;
  int j = threadIdx.x;
  float acc = 0.f;
#pragma unroll 8
  for (int k = 0; k < N_FEAT; ++k)
    acc = fmaf(W[k * LATENT + i], W[k * LATENT + j], acc);
  if (j == i) acc += expf(log_var[0]);
  M[i * LATENT + j] = acc;
}

// ---------------------------------------------------------------------------
// Kernel P: Wt[n][k] = bf16(W[k][n])  -- transposed bf16 copy for coalesced
// B-tile staging in k_main. LDS-tiled transpose, 48 blocks x 64 k-cols.
// ---------------------------------------------------------------------------
__global__ __launch_bounds__(256) void k_wt(const float* __restrict__ W,
                                            unsigned short* __restrict__ Wt) {
  __shared__ __align__(16) unsigned short T[128][72];
  int t = threadIdx.x;
  int k0 = blockIdx.x * 64;
  int kl = t >> 2;   // 0..63 local k
  int q = t & 3;     // 32-col quarter
  const float* src = W + (size_t)(k0 + kl) * LATENT + q * 32;
#pragma unroll
  for (int c = 0; c < 8; ++c) {
    float4 v = *(const float4*)(src + c * 4);
    T[q * 32 + c * 4 + 0][kl] = f2bf(v.x);
    T[q * 32 + c * 4 + 1][kl] = f2bf(v.y);
    T[q * 32 + c * 4 + 2][kl] = f2bf(v.z);
    T[q * 32 + c * 4 + 3][kl] = f2bf(v.w);
  }
  __syncthreads();
  int n = t >> 1, h = t & 1;
  uint4* dst = (uint4*)(Wt + (size_t)n * N_FEAT + k0 + h * 32);
  const uint4* s = (const uint4*)&T[n][h * 32];
#pragma unroll
  for (int c = 0; c < 4; ++c) dst[c] = s[c];
}

// ---------------------------------------------------------------------------
// Kernel B: in-place Gauss-Jordan inverse of M (SPD, no pivoting) + logdet.
// Single block, 256 threads, matrix in LDS. Knowingly serial (128 steps);
// placeholder to be optimized/hidden in later rounds.
// scal[0] = -0.5*(n*log2pi + (n-k)*lv + logdetM),  scal[1] = 1/sigma^2
// ---------------------------------------------------------------------------
__global__ __launch_bounds__(256) void k_inv(float* __restrict__ M,
                                             float* __restrict__ scal,
                                             const float* __restrict__ log_var) {
  __shared__ __align__(16) float A[128][132];
  int t = threadIdx.x;
  for (int idx = t; idx < 128 * 128; idx += 256)
    A[idx >> 7][idx & 127] = M[idx];
  __syncthreads();
  float logdet = 0.f;
  int i = t >> 1;
  int jb = (t & 1) << 6;  // 64-col half
  for (int k = 0; k < 128; ++k) {
    float d = A[k][k];
    float ip = 1.f / d;
    if (t == 0) logdet += logf(d);
    if (t < 128 && t != k) A[k][t] *= ip;  // scale pivot row (j != k)
    __syncthreads();
    if (i != k) {
      float e = A[i][k];
#pragma unroll
      for (int c = 0; c < 16; ++c) {
        int jj = jb + c * 4;
        f32x4 p = *(f32x4*)&A[k][jj];
        f32x4 v = *(f32x4*)&A[i][jj];
        v -= e * p;
        *(f32x4*)&A[i][jj] = v;
      }
      if (k >= jb && k < jb + 64) A[i][k] = -e * ip;  // column-k fixup
    }
    if (t == 0) A[k][k] = ip;
    __syncthreads();
  }
  for (int idx = t; idx < 128 * 128; idx += 256)
    M[idx] = A[idx >> 7][idx & 127];
  if (t == 0) {
    float lv = log_var[0];
    scal[0] = -0.5f * (N_FEAT * LOG2PI + (float)(N_FEAT - LATENT) * lv + logdet);
    scal[1] = expf(-lv);
  }
}

// ---------------------------------------------------------------------------
// Kernel C: per block of 32 batch rows:
//   stage res = ex - mean (fp32), accumulate ||res||^2, pack bf16 -> LDS
//   T = res * W  via mfma_f32_16x16x32_bf16 (B-tile from Wt: [n][k] layout)
//   quad core: q_b = t_b^T Minv t_b   (fp32, Minv from L2)
//   out_b = scal0 - 0.5*scal1*(sumsq_b - q_b)
// ---------------------------------------------------------------------------
__global__ __launch_bounds__(256) void k_main(const float* __restrict__ ex,
                                              const float* __restrict__ mean,
                                              const unsigned short* __restrict__ Wt,
                                              const float* __restrict__ Minv,
                                              const float* __restrict__ scal,
                                              float* __restrict__ out) {
  __shared__ __align__(16) unsigned short As[32][72];   // [row][k] bf16, +8 pad
  __shared__ __align__(16) unsigned short Bs[128][72];  // [n][k] bf16, +8 pad
  __shared__ __align__(16) float Ts[32][132];           // T tile fp32, +4 pad
  __shared__ float rs[32];                              // row sumsq
  int t = threadIdx.x;
  int r0 = blockIdx.x * 32;

  // A staging: thread -> (row, 8-col segment)
  int arow = t >> 3, aseg = t & 7;
  const float* ep = ex + (size_t)(r0 + arow) * N_FEAT + aseg * 8;
  const float* mp = mean + aseg * 8;
  // B staging: thread -> (n row, 32-col half)
  int brow = t >> 1, bh = t & 1;
  const unsigned short* wp = Wt + (size_t)brow * N_FEAT + bh * 32;

  // wave/fragment indices: wave w covers rows [16*wr,+16), cols [64*wc,+64)
  int lane = t & 63, w = t >> 6;
  int wr = w & 1, wc = w >> 1;
  int fr = lane & 15, fq = lane >> 4;

  f32x4 acc[4];
#pragma unroll
  for (int ct = 0; ct < 4; ++ct) acc[ct] = (f32x4){0.f, 0.f, 0.f, 0.f};
  float sumsq = 0.f;

  for (int kk = 0; kk < N_FEAT; kk += 64) {
    // ---- stage A: res = ex - mean, sumsq, bf16 pack ----
    float4 m0 = *(const float4*)(mp + kk);
    float4 m1 = *(const float4*)(mp + kk + 4);
    float4 e0 = *(const float4*)(ep + kk);
    float4 e1 = *(const float4*)(ep + kk + 4);
    float r_[8] = {e0.x - m0.x, e0.y - m0.y, e0.z - m0.z, e0.w - m0.w,
                   e1.x - m1.x, e1.y - m1.y, e1.z - m1.z, e1.w - m1.w};
#pragma unroll
    for (int c = 0; c < 8; ++c) sumsq = fmaf(r_[c], r_[c], sumsq);
    uint4 pk;
    pk.x = (unsigned)f2bf(r_[0]) | ((unsigned)f2bf(r_[1]) << 16);
    pk.y = (unsigned)f2bf(r_[2]) | ((unsigned)f2bf(r_[3]) << 16);
    pk.z = (unsigned)f2bf(r_[4]) | ((unsigned)f2bf(r_[5]) << 16);
    pk.w = (unsigned)f2bf(r_[6]) | ((unsigned)f2bf(r_[7]) << 16);
    *(uint4*)&As[arow][aseg * 8] = pk;

    // ---- stage B: copy Wt tile ----
    const uint4* bsrc = (const uint4*)(wp + kk);
    uint4* bdst = (uint4*)&Bs[brow][bh * 32];
#pragma unroll
    for (int c = 0; c < 4; ++c) bdst[c] = bsrc[c];

    __syncthreads();

    // ---- MFMA: 2 k-steps x 4 col-tiles ----
    short8 a0 = *(const short8*)&As[wr * 16 + fr][fq * 8];
    short8 a1 = *(const short8*)&As[wr * 16 + fr][32 + fq * 8];
#pragma unroll
    for (int ct = 0; ct < 4; ++ct) {
      const unsigned short* bp = &Bs[wc * 64 + ct * 16 + fr][fq * 8];
      short8 b0 = *(const short8*)bp;
      short8 b1 = *(const short8*)(bp + 32);
      acc[ct] = __builtin_amdgcn_mfma_f32_16x16x32_bf16(a0, b0, acc[ct], 0, 0, 0);
      acc[ct] = __builtin_amdgcn_mfma_f32_16x16x32_bf16(a1, b1, acc[ct], 0, 0, 0);
    }
    __syncthreads();
  }

  // ---- row sumsq reduce (8 threads per row are adjacent lanes) ----
  sumsq += __shfl_xor(sumsq, 1);
  sumsq += __shfl_xor(sumsq, 2);
  sumsq += __shfl_xor(sumsq, 4);
  if (aseg == 0) rs[arow] = sumsq;

  // ---- spill T tile: D layout col=lane&15, row=quad*4+reg ----
#pragma unroll
  for (int ct = 0; ct < 4; ++ct)
#pragma unroll
    for (int ii = 0; ii < 4; ++ii)
      Ts[wr * 16 + fq * 4 + ii][wc * 64 + ct * 16 + fr] = acc[ct][ii];
  __syncthreads();

  // ---- epilogue: q = t^T Minv t ; thread -> (row pair, 8-col group) ----
  int rp = t >> 4, cg = t & 15;
  int ra = 2 * rp, rb = ra + 1;
  int c0 = cg * 8;
  float ya[8] = {0, 0, 0, 0, 0, 0, 0, 0};
  float yb[8] = {0, 0, 0, 0, 0, 0, 0, 0};
#pragma unroll 4
  for (int j = 0; j < 128; ++j) {
    float tav = Ts[ra][j];
    float tbv = Ts[rb][j];
    float4 v0 = *(const float4*)(Minv + j * LATENT + c0);
    float4 v1 = *(const float4*)(Minv + j * LATENT + c0 + 4);
    ya[0] = fmaf(tav, v0.x, ya[0]); ya[1] = fmaf(tav, v0.y, ya[1]);
    ya[2] = fmaf(tav, v0.z, ya[2]); ya[3] = fmaf(tav, v0.w, ya[3]);
    ya[4] = fmaf(tav, v1.x, ya[4]); ya[5] = fmaf(tav, v1.y, ya[5]);
    ya[6] = fmaf(tav, v1.z, ya[6]); ya[7] = fmaf(tav, v1.w, ya[7]);
    yb[0] = fmaf(tbv, v0.x, yb[0]); yb[1] = fmaf(tbv, v0.y, yb[1]);
    yb[2] = fmaf(tbv, v0.z, yb[2]); yb[3] = fmaf(tbv, v0.w, yb[3]);
    yb[4] = fmaf(tbv, v1.x, yb[4]); yb[5] = fmaf(tbv, v1.y, yb[5]);
    yb[6] = fmaf(tbv, v1.z, yb[6]); yb[7] = fmaf(tbv, v1.w, yb[7]);
  }
  float q0 = 0.f, q1 = 0.f;
#pragma unroll
  for (int c = 0; c < 8; ++c) {
    q0 = fmaf(ya[c], Ts[ra][c0 + c], q0);
    q1 = fmaf(yb[c], Ts[rb][c0 + c], q1);
  }
  q0 += __shfl_xor(q0, 1); q0 += __shfl_xor(q0, 2);
  q0 += __shfl_xor(q0, 4); q0 += __shfl_xor(q0, 8);
  q1 += __shfl_xor(q1, 1); q1 += __shfl_xor(q1, 2);
  q1 += __shfl_xor(q1, 4); q1 += __shfl_xor(q1, 8);
  if (cg == 0) {
    float cc = scal[0], is2 = scal[1];
    out[r0 + ra] = cc - 0.5f * is2 * (rs[ra] - q0);
    out[r0 + rb] = cc - 0.5f * is2 * (rs[rb] - q1);
  }
}

// ---------------------------------------------------------------------------
extern "C" void kernel_launch(void* const* d_in, const int* in_sizes, int n_in,
                              void* d_out, int out_size, void* d_ws, size_t ws_size,
                              hipStream_t stream) {
  (void)in_sizes; (void)n_in; (void)out_size; (void)ws_size;
  const float* ex   = (const float*)d_in[0];
  const float* W    = (const float*)d_in[1];
  const float* lv   = (const float*)d_in[2];
  const float* mean = (const float*)d_in[3];
  float* out = (float*)d_out;

  // ws layout: [0,64KB) M/Minv fp32; [64KB,+64B) scalars; then Wt bf16 (768KB)
  float* M = (float*)d_ws;
  float* scal = M + 128 * 128;
  unsigned short* Wt = (unsigned short*)(scal + 16);

  k_gram<<<128, 128, 0, stream>>>(W, lv, M);
  k_wt<<<48, 256, 0, stream>>>(W, Wt);
  k_inv<<<1, 256, 0, stream>>>(M, scal, lv);
  k_main<<<256, 256, 0, stream>>>(ex, mean, Wt, M, scal, out);
}

// Round 2
// 300.392 us; speedup vs baseline: 1.8042x; 1.8042x over previous
//
#include <hip/hip_runtime.h>
#include <hip/hip_bf16.h>

#define N_FEAT 3072
#define LATENT 128
#define LOG2PI 1.8378770664093453f

typedef __attribute__((ext_vector_type(8))) short short8;
typedef __attribute__((ext_vector_type(4))) float f32x4;

__device__ __forceinline__ unsigned short f2bf(float x) {
  unsigned int u = __float_as_uint(x);
  u += 0x7FFFu + ((u >> 16) & 1u);
  return (unsigned short)(u >> 16);
}

// ---------------------------------------------------------------------------
// Kernel A v2: M += W_chunk^T W_chunk via register outer-product tiles.
// 48 blocks x 64 k-rows each; M must be zeroed first; sigma^2 added in k_inv.
// ---------------------------------------------------------------------------
#define GR_CHUNK 64
__global__ __launch_bounds__(256) void k_gram(const float* __restrict__ W,
                                              float* __restrict__ M) {
  __shared__ __align__(16) float Ws[GR_CHUNK * 128];
  int t = threadIdx.x;
  const float* src = W + (size_t)blockIdx.x * GR_CHUNK * 128;
#pragma unroll
  for (int c = 0; c < 8; ++c)
    ((float4*)Ws)[t + 256 * c] = ((const float4*)src)[t + 256 * c];
  __syncthreads();
  int tr = t >> 4, tc = t & 15;
  float acc[8][8];
#pragma unroll
  for (int r = 0; r < 8; ++r)
#pragma unroll
    for (int c = 0; c < 8; ++c) acc[r][c] = 0.f;
#pragma unroll 2
  for (int k = 0; k < GR_CHUNK; ++k) {
    f32x4 a0 = *(f32x4*)&Ws[k * 128 + 8 * tr];
    f32x4 a1 = *(f32x4*)&Ws[k * 128 + 8 * tr + 4];
    f32x4 b0 = *(f32x4*)&Ws[k * 128 + 8 * tc];
    f32x4 b1 = *(f32x4*)&Ws[k * 128 + 8 * tc + 4];
    float av[8] = {a0.x, a0.y, a0.z, a0.w, a1.x, a1.y, a1.z, a1.w};
    float bv[8] = {b0.x, b0.y, b0.z, b0.w, b1.x, b1.y, b1.z, b1.w};
#pragma unroll
    for (int r = 0; r < 8; ++r)
#pragma unroll
      for (int c = 0; c < 8; ++c) acc[r][c] = fmaf(av[r], bv[c], acc[r][c]);
  }
  float* dst = M + (size_t)(8 * tr) * 128 + 8 * tc;
#pragma unroll
  for (int r = 0; r < 8; ++r)
#pragma unroll
    for (int c = 0; c < 8; ++c) atomicAdd(&dst[r * 128 + c], acc[r][c]);
}

// ---------------------------------------------------------------------------
// Kernel P: Wt[n][k] = bf16(W[k][n])  (unchanged)
// ---------------------------------------------------------------------------
__global__ __launch_bounds__(256) void k_wt(const float* __restrict__ W,
                                            unsigned short* __restrict__ Wt) {
  __shared__ __align__(16) unsigned short T[128][72];
  int t = threadIdx.x;
  int k0 = blockIdx.x * 64;
  int kl = t >> 2;
  int q = t & 3;
  const float* src = W + (size_t)(k0 + kl) * LATENT + q * 32;
#pragma unroll
  for (int c = 0; c < 8; ++c) {
    float4 v = *(const float4*)(src + c * 4);
    T[q * 32 + c * 4 + 0][kl] = f2bf(v.x);
    T[q * 32 + c * 4 + 1][kl] = f2bf(v.y);
    T[q * 32 + c * 4 + 2][kl] = f2bf(v.z);
    T[q * 32 + c * 4 + 3][kl] = f2bf(v.w);
  }
  __syncthreads();
  int n = t >> 1, h = t & 1;
  uint4* dst = (uint4*)(Wt + (size_t)n * N_FEAT + k0 + h * 32);
  const uint4* s = (const uint4*)&T[n][h * 32];
#pragma unroll
  for (int c = 0; c < 4; ++c) dst[c] = s[c];
}

// ---------------------------------------------------------------------------
// Kernel B v2: Gauss-Jordan inverse with the matrix held in REGISTERS.
// 256 threads = 16x16 grid of 8x8 register tiles. Per pivot step, the pivot
// row/col (+diag) are broadcast through double-buffered LDS; ONE barrier per
// step. Inner 8-step loop unrolled so all register indices are static.
// Adds sigma^2 I at load; emits logdet and folded scalars.
// ---------------------------------------------------------------------------
__global__ __launch_bounds__(256) void k_inv(float* __restrict__ M,
                                             float* __restrict__ scal,
                                             const float* __restrict__ log_var) {
  __shared__ float prow[2][128];
  __shared__ float pcol[2][128];
  __shared__ float dbuf[2];
  int t = threadIdx.x;
  int tr = t >> 4, tc = t & 15;
  float lv = log_var[0];
  float sig2 = expf(lv);
  float a[8][8];
  const float* src = M + (size_t)(8 * tr) * 128 + 8 * tc;
#pragma unroll
  for (int r = 0; r < 8; ++r) {
    f32x4 v0 = *(const f32x4*)(src + r * 128);
    f32x4 v1 = *(const f32x4*)(src + r * 128 + 4);
    a[r][0] = v0.x; a[r][1] = v0.y; a[r][2] = v0.z; a[r][3] = v0.w;
    a[r][4] = v1.x; a[r][5] = v1.y; a[r][6] = v1.z; a[r][7] = v1.w;
  }
  if (tr == tc) {
#pragma unroll
    for (int r = 0; r < 8; ++r) a[r][r] += sig2;
  }
  // stage pivots for k=0
  if (tr == 0) {
#pragma unroll
    for (int c = 0; c < 8; ++c) prow[0][8 * tc + c] = a[0][c];
  }
  if (tc == 0) {
#pragma unroll
    for (int r = 0; r < 8; ++r) pcol[0][8 * tr + r] = a[r][0];
  }
  if (t == 0) dbuf[0] = a[0][0];
  __syncthreads();

  float logdet = 0.f;
  for (int kb = 0; kb < 16; ++kb) {
#pragma unroll
    for (int lk = 0; lk < 8; ++lk) {
      const int k = kb * 8 + lk;
      const int buf = k & 1;
      float d = dbuf[buf];
      if (t == 0) logdet += logf(d);
      float p = 1.0f / d;
      float pr[8], pc[8];
#pragma unroll
      for (int c = 0; c < 8; ++c) pr[c] = prow[buf][8 * tc + c] * p;
#pragma unroll
      for (int r = 0; r < 8; ++r) pc[r] = pcol[buf][8 * tr + r];
      // generic rank-1 update
#pragma unroll
      for (int r = 0; r < 8; ++r)
#pragma unroll
        for (int c = 0; c < 8; ++c) a[r][c] = fmaf(-pc[r], pr[c], a[r][c]);
      // fixups (pivot row / pivot col / diag), using saved old pivot values
      bool myrow = (tr == (k >> 3));
      bool mycol = (tc == (k >> 3));
      if (myrow) {
#pragma unroll
        for (int c = 0; c < 8; ++c) a[lk][c] = pr[c];
      }
      if (mycol) {
#pragma unroll
        for (int r = 0; r < 8; ++r) a[r][lk] = -p * pc[r];
      }
      if (myrow && mycol) a[lk][lk] = p;
      // stage pivots for k+1 (static register index: nl = (lk+1)&7)
      if (k + 1 < 128) {
        const int nb = buf ^ 1;
        const int nl = (lk + 1) & 7;
        const int nr = (k + 1) >> 3;
        if (tr == nr) {
#pragma unroll
          for (int c = 0; c < 8; ++c) prow[nb][8 * tc + c] = a[nl][c];
        }
        if (tc == nr) {
#pragma unroll
          for (int r = 0; r < 8; ++r) pcol[nb][8 * tr + r] = a[r][nl];
        }
        if (tr == nr && tc == nr) dbuf[nb] = a[nl][nl];
      }
      __syncthreads();
    }
  }

  float* dst = M + (size_t)(8 * tr) * 128 + 8 * tc;
#pragma unroll
  for (int r = 0; r < 8; ++r) {
    f32x4 v0 = {a[r][0], a[r][1], a[r][2], a[r][3]};
    f32x4 v1 = {a[r][4], a[r][5], a[r][6], a[r][7]};
    *(f32x4*)(dst + r * 128) = v0;
    *(f32x4*)(dst + r * 128 + 4) = v1;
  }
  if (t == 0) {
    scal[0] = -0.5f * (N_FEAT * LOG2PI + (float)(N_FEAT - LATENT) * lv + logdet);
    scal[1] = expf(-lv);
  }
}

// ---------------------------------------------------------------------------
// Kernel C: fused res/sumsq/bf16 staging -> MFMA T = res*W -> quad epilogue.
// (unchanged from round 1)
// ---------------------------------------------------------------------------
__global__ __launch_bounds__(256) void k_main(const float* __restrict__ ex,
                                              const float* __restrict__ mean,
                                              const unsigned short* __restrict__ Wt,
                                              const float* __restrict__ Minv,
                                              const float* __restrict__ scal,
                                              float* __restrict__ out) {
  __shared__ __align__(16) unsigned short As[32][72];
  __shared__ __align__(16) unsigned short Bs[128][72];
  __shared__ __align__(16) float Ts[32][132];
  __shared__ float rs[32];
  int t = threadIdx.x;
  int r0 = blockIdx.x * 32;

  int arow = t >> 3, aseg = t & 7;
  const float* ep = ex + (size_t)(r0 + arow) * N_FEAT + aseg * 8;
  const float* mp = mean + aseg * 8;
  int brow = t >> 1, bh = t & 1;
  const unsigned short* wp = Wt + (size_t)brow * N_FEAT + bh * 32;

  int lane = t & 63, w = t >> 6;
  int wr = w & 1, wc = w >> 1;
  int fr = lane & 15, fq = lane >> 4;

  f32x4 acc[4];
#pragma unroll
  for (int ct = 0; ct < 4; ++ct) acc[ct] = (f32x4){0.f, 0.f, 0.f, 0.f};
  float sumsq = 0.f;

  for (int kk = 0; kk < N_FEAT; kk += 64) {
    float4 m0 = *(const float4*)(mp + kk);
    float4 m1 = *(const float4*)(mp + kk + 4);
    float4 e0 = *(const float4*)(ep + kk);
    float4 e1 = *(const float4*)(ep + kk + 4);
    float r_[8] = {e0.x - m0.x, e0.y - m0.y, e0.z - m0.z, e0.w - m0.w,
                   e1.x - m1.x, e1.y - m1.y, e1.z - m1.z, e1.w - m1.w};
#pragma unroll
    for (int c = 0; c < 8; ++c) sumsq = fmaf(r_[c], r_[c], sumsq);
    uint4 pk;
    pk.x = (unsigned)f2bf(r_[0]) | ((unsigned)f2bf(r_[1]) << 16);
    pk.y = (unsigned)f2bf(r_[2]) | ((unsigned)f2bf(r_[3]) << 16);
    pk.z = (unsigned)f2bf(r_[4]) | ((unsigned)f2bf(r_[5]) << 16);
    pk.w = (unsigned)f2bf(r_[6]) | ((unsigned)f2bf(r_[7]) << 16);
    *(uint4*)&As[arow][aseg * 8] = pk;

    const uint4* bsrc = (const uint4*)(wp + kk);
    uint4* bdst = (uint4*)&Bs[brow][bh * 32];
#pragma unroll
    for (int c = 0; c < 4; ++c) bdst[c] = bsrc[c];

    __syncthreads();

    short8 a0 = *(const short8*)&As[wr * 16 + fr][fq * 8];
    short8 a1 = *(const short8*)&As[wr * 16 + fr][32 + fq * 8];
#pragma unroll
    for (int ct = 0; ct < 4; ++ct) {
      const unsigned short* bp = &Bs[wc * 64 + ct * 16 + fr][fq * 8];
      short8 b0 = *(const short8*)bp;
      short8 b1 = *(const short8*)(bp + 32);
      acc[ct] = __builtin_amdgcn_mfma_f32_16x16x32_bf16(a0, b0, acc[ct], 0, 0, 0);
      acc[ct] = __builtin_amdgcn_mfma_f32_16x16x32_bf16(a1, b1, acc[ct], 0, 0, 0);
    }
    __syncthreads();
  }

  sumsq += __shfl_xor(sumsq, 1);
  sumsq += __shfl_xor(sumsq, 2);
  sumsq += __shfl_xor(sumsq, 4);
  if (aseg == 0) rs[arow] = sumsq;

#pragma unroll
  for (int ct = 0; ct < 4; ++ct)
#pragma unroll
    for (int ii = 0; ii < 4; ++ii)
      Ts[wr * 16 + fq * 4 + ii][wc * 64 + ct * 16 + fr] = acc[ct][ii];
  __syncthreads();

  int rp = t >> 4, cg = t & 15;
  int ra = 2 * rp, rb = ra + 1;
  int c0 = cg * 8;
  float ya[8] = {0, 0, 0, 0, 0, 0, 0, 0};
  float yb[8] = {0, 0, 0, 0, 0, 0, 0, 0};
#pragma unroll 4
  for (int j = 0; j < 128; ++j) {
    float tav = Ts[ra][j];
    float tbv = Ts[rb][j];
    float4 v0 = *(const float4*)(Minv + j * LATENT + c0);
    float4 v1 = *(const float4*)(Minv + j * LATENT + c0 + 4);
    ya[0] = fmaf(tav, v0.x, ya[0]); ya[1] = fmaf(tav, v0.y, ya[1]);
    ya[2] = fmaf(tav, v0.z, ya[2]); ya[3] = fmaf(tav, v0.w, ya[3]);
    ya[4] = fmaf(tav, v1.x, ya[4]); ya[5] = fmaf(tav, v1.y, ya[5]);
    ya[6] = fmaf(tav, v1.z, ya[6]); ya[7] = fmaf(tav, v1.w, ya[7]);
    yb[0] = fmaf(tbv, v0.x, yb[0]); yb[1] = fmaf(tbv, v0.y, yb[1]);
    yb[2] = fmaf(tbv, v0.z, yb[2]); yb[3] = fmaf(tbv, v0.w, yb[3]);
    yb[4] = fmaf(tbv, v1.x, yb[4]); yb[5] = fmaf(tbv, v1.y, yb[5]);
    yb[6] = fmaf(tbv, v1.z, yb[6]); yb[7] = fmaf(tbv, v1.w, yb[7]);
  }
  float q0 = 0.f, q1 = 0.f;
#pragma unroll
  for (int c = 0; c < 8; ++c) {
    q0 = fmaf(ya[c], Ts[ra][c0 + c], q0);
    q1 = fmaf(yb[c], Ts[rb][c0 + c], q1);
  }
  q0 += __shfl_xor(q0, 1); q0 += __shfl_xor(q0, 2);
  q0 += __shfl_xor(q0, 4); q0 += __shfl_xor(q0, 8);
  q1 += __shfl_xor(q1, 1); q1 += __shfl_xor(q1, 2);
  q1 += __shfl_xor(q1, 4); q1 += __shfl_xor(q1, 8);
  if (cg == 0) {
    float cc = scal[0], is2 = scal[1];
    out[r0 + ra] = cc - 0.5f * is2 * (rs[ra] - q0);
    out[r0 + rb] = cc - 0.5f * is2 * (rs[rb] - q1);
  }
}

// ---------------------------------------------------------------------------
extern "C" void kernel_launch(void* const* d_in, const int* in_sizes, int n_in,
                              void* d_out, int out_size, void* d_ws, size_t ws_size,
                              hipStream_t stream) {
  (void)in_sizes; (void)n_in; (void)out_size; (void)ws_size;
  const float* ex   = (const float*)d_in[0];
  const float* W    = (const float*)d_in[1];
  const float* lv   = (const float*)d_in[2];
  const float* mean = (const float*)d_in[3];
  float* out = (float*)d_out;

  float* M = (float*)d_ws;
  float* scal = M + 128 * 128;
  unsigned short* Wt = (unsigned short*)(scal + 16);

  hipMemsetAsync(M, 0, 128 * 128 * sizeof(float), stream);
  k_gram<<<N_FEAT / GR_CHUNK, 256, 0, stream>>>(W, M);
  k_wt<<<48, 256, 0, stream>>>(W, Wt);
  k_inv<<<1, 256, 0, stream>>>(M, scal, lv);
  k_main<<<256, 256, 0, stream>>>(ex, mean, Wt, M, scal, out);
}

// Round 3
// 267.256 us; speedup vs baseline: 2.0279x; 1.1240x over previous
//
#include <hip/hip_runtime.h>
#include <hip/hip_bf16.h>

#define N_FEAT 3072
#define LATENT 128
#define LOG2PI 1.8378770664093453f
#define GB 512      // gemm blocks (256 row-groups x 2 K-halves)
#define KHALF 1536

typedef __attribute__((ext_vector_type(8))) short short8;
typedef __attribute__((ext_vector_type(4))) float f32x4;

__device__ __forceinline__ unsigned short f2bf(float x) {
  unsigned int u = __float_as_uint(x);
  u += 0x7FFFu + ((u >> 16) & 1u);
  return (unsigned short)(u >> 16);
}

// ---------------------------------------------------------------------------
// k_prep: fused  (a) M += Wchunk^T Wchunk  (atomics, M pre-zeroed)
//                (b) Wt[n][k] = bf16(W[k][n])
// 48 blocks x 64 k-rows; W read exactly once.
// ---------------------------------------------------------------------------
#define GR_CHUNK 64
__global__ __launch_bounds__(256) void k_prep(const float* __restrict__ W,
                                              float* __restrict__ M,
                                              unsigned short* __restrict__ Wt) {
  __shared__ __align__(16) float Ws[GR_CHUNK * 128];
  int t = threadIdx.x;
  int k0 = blockIdx.x * GR_CHUNK;
  const float* src = W + (size_t)k0 * 128;
#pragma unroll
  for (int c = 0; c < 8; ++c)
    ((float4*)Ws)[t + 256 * c] = ((const float4*)src)[t + 256 * c];
  __syncthreads();
  // --- gram: 8x8 register tiles ---
  int tr = t >> 4, tc = t & 15;
  float acc[8][8];
#pragma unroll
  for (int r = 0; r < 8; ++r)
#pragma unroll
    for (int c = 0; c < 8; ++c) acc[r][c] = 0.f;
#pragma unroll 2
  for (int k = 0; k < GR_CHUNK; ++k) {
    f32x4 a0 = *(f32x4*)&Ws[k * 128 + 8 * tr];
    f32x4 a1 = *(f32x4*)&Ws[k * 128 + 8 * tr + 4];
    f32x4 b0 = *(f32x4*)&Ws[k * 128 + 8 * tc];
    f32x4 b1 = *(f32x4*)&Ws[k * 128 + 8 * tc + 4];
    float av[8] = {a0.x, a0.y, a0.z, a0.w, a1.x, a1.y, a1.z, a1.w};
    float bv[8] = {b0.x, b0.y, b0.z, b0.w, b1.x, b1.y, b1.z, b1.w};
#pragma unroll
    for (int r = 0; r < 8; ++r)
#pragma unroll
      for (int c = 0; c < 8; ++c) acc[r][c] = fmaf(av[r], bv[c], acc[r][c]);
  }
  float* dst = M + (size_t)(8 * tr) * 128 + 8 * tc;
#pragma unroll
  for (int r = 0; r < 8; ++r)
#pragma unroll
    for (int c = 0; c < 8; ++c) atomicAdd(&dst[r * 128 + c], acc[r][c]);
  // --- Wt conversion: thread -> (col n, 32-k half) ---
  int n = t >> 1, h = t & 1;
  unsigned pk[16];
#pragma unroll
  for (int c = 0; c < 16; ++c)
    pk[c] = (unsigned)f2bf(Ws[(h * 32 + 2 * c) * 128 + n]) |
            ((unsigned)f2bf(Ws[(h * 32 + 2 * c + 1) * 128 + n]) << 16);
  uint4* wd = (uint4*)(Wt + (size_t)n * N_FEAT + k0 + h * 32);
#pragma unroll
  for (int c = 0; c < 4; ++c)
    wd[c] = make_uint4(pk[4 * c], pk[4 * c + 1], pk[4 * c + 2], pk[4 * c + 3]);
}

// ---------------------------------------------------------------------------
// k_gemm: blocks 0..511: T += res*W (split-K halves, atomics) + sumsq.
//         block 512:     in-place Gauss-Jordan inverse of M (+sigma^2 I),
//                        logdet, folded scalars (runs concurrently).
// 512 threads, 32 rows/block, BK=64, double-buffered LDS, 1 barrier/iter,
// XOR-swizzled As/Bs to kill bank conflicts.
// ---------------------------------------------------------------------------
__global__ __launch_bounds__(512, 4) void k_gemm(
    const float* __restrict__ ex, const float* __restrict__ mean,
    const unsigned short* __restrict__ Wt, float* __restrict__ M,
    float* __restrict__ scal, const float* __restrict__ log_var,
    float* __restrict__ T, float* __restrict__ sumsq) {
  __shared__ __align__(16) unsigned short As[2][32][72];
  __shared__ __align__(16) unsigned short Bs[2][128][72];
  __shared__ float prow[2][128], pcol[2][128], dbuf[2], diag[128], red[2];
  int t = threadIdx.x;

  if (blockIdx.x == GB) {
    // ================= inverse path (threads 0..255 active) =================
    bool act = t < 256;
    int itr = t >> 4, itc = t & 15;
    float lv = log_var[0];
    float sig2 = expf(lv);
    float a[8][8];
    if (act) {
      const float* srcM = M + (size_t)(8 * itr) * 128 + 8 * itc;
#pragma unroll
      for (int r = 0; r < 8; ++r) {
        f32x4 v0 = *(const f32x4*)(srcM + r * 128);
        f32x4 v1 = *(const f32x4*)(srcM + r * 128 + 4);
        a[r][0] = v0.x; a[r][1] = v0.y; a[r][2] = v0.z; a[r][3] = v0.w;
        a[r][4] = v1.x; a[r][5] = v1.y; a[r][6] = v1.z; a[r][7] = v1.w;
      }
      if (itr == itc) {
#pragma unroll
        for (int r = 0; r < 8; ++r) a[r][r] += sig2;
      }
      if (itr == 0) {
#pragma unroll
        for (int c = 0; c < 8; ++c) prow[0][8 * itc + c] = a[0][c];
      }
      if (itc == 0) {
#pragma unroll
        for (int r = 0; r < 8; ++r) pcol[0][8 * itr + r] = a[r][0];
      }
      if (t == 0) dbuf[0] = a[0][0];
    }
    __syncthreads();
    for (int kb = 0; kb < 16; ++kb) {
#pragma unroll
      for (int lk = 0; lk < 8; ++lk) {
        const int k = kb * 8 + lk;
        const int buf = k & 1;
        if (act) {
          float d = dbuf[buf];
          if (t == 0) diag[k] = d;
          float p = 1.0f / d;
          float pr[8], pc[8];
#pragma unroll
          for (int c = 0; c < 8; ++c) pr[c] = prow[buf][8 * itc + c] * p;
#pragma unroll
          for (int r = 0; r < 8; ++r) pc[r] = pcol[buf][8 * itr + r];
#pragma unroll
          for (int r = 0; r < 8; ++r)
#pragma unroll
            for (int c = 0; c < 8; ++c) a[r][c] = fmaf(-pc[r], pr[c], a[r][c]);
          bool myrow = (itr == (k >> 3));
          bool mycol = (itc == (k >> 3));
          if (myrow) {
#pragma unroll
            for (int c = 0; c < 8; ++c) a[lk][c] = pr[c];
          }
          if (mycol) {
#pragma unroll
            for (int r = 0; r < 8; ++r) a[r][lk] = -p * pc[r];
          }
          if (myrow && mycol) a[lk][lk] = p;
          if (k + 1 < 128) {
            const int nb = buf ^ 1;
            const int nl = (lk + 1) & 7;
            const int nr = (k + 1) >> 3;
            if (itr == nr) {
#pragma unroll
              for (int c = 0; c < 8; ++c) prow[nb][8 * itc + c] = a[nl][c];
            }
            if (itc == nr) {
#pragma unroll
              for (int r = 0; r < 8; ++r) pcol[nb][8 * itr + r] = a[r][nl];
            }
            if (itr == nr && itc == nr) dbuf[nb] = a[nl][nl];
          }
        }
        __syncthreads();
      }
    }
    if (act) {
      float* dst = M + (size_t)(8 * itr) * 128 + 8 * itc;
#pragma unroll
      for (int r = 0; r < 8; ++r) {
        f32x4 v0 = {a[r][0], a[r][1], a[r][2], a[r][3]};
        f32x4 v1 = {a[r][4], a[r][5], a[r][6], a[r][7]};
        *(f32x4*)(dst + r * 128) = v0;
        *(f32x4*)(dst + r * 128 + 4) = v1;
      }
    }
    float ld = 0.f;
    if (t < 128) ld = logf(diag[t]);
#pragma unroll
    for (int o = 1; o < 64; o <<= 1) ld += __shfl_xor(ld, o);
    if (t == 0) red[0] = ld;
    if (t == 64) red[1] = ld;
    __syncthreads();
    if (t == 0) {
      scal[0] = -0.5f * (N_FEAT * LOG2PI + (float)(N_FEAT - LATENT) * lv +
                         (red[0] + red[1]));
      scal[1] = expf(-lv);
    }
    return;
  }

  // ================= GEMM path =================
  int half = blockIdx.x >> 8;
  int r0 = (blockIdx.x & 255) * 32;
  int kbase = half * KHALF;

  // A staging: thread -> (row, 4-float seg); XOR-swizzled 8-elem groups
  int arow = t >> 4, aseg = t & 15;
  const float* ep = ex + (size_t)(r0 + arow) * N_FEAT + kbase + aseg * 4;
  const float* mp = mean + kbase + aseg * 4;
  int sA = (((aseg >> 1) + arow) & 7) * 8 + (aseg & 1) * 4;
  // B staging: thread -> (n row, 16-elem quarter); XOR-swizzled 16-elem chunks
  int brow = t >> 2, bq = t & 3;
  const unsigned short* wp = Wt + (size_t)brow * N_FEAT + kbase + bq * 16;
  int sB = ((bq + brow) & 3) * 16;

  // fragment indices: wave w -> rows wr*16, col-pair wc*32 (+0/+16)
  int lane = t & 63, w = t >> 6;
  int wr = w & 1, wc = w >> 1;
  int fr = lane & 15, fq = lane >> 4;
  int ar = wr * 16 + fr;
  int cA0 = ((fq + ar) & 7) * 8;
  int cA1 = ((fq + 4 + ar) & 7) * 8;
  int n0 = wc * 32 + fr, n1 = n0 + 16;
  int c00 = (((fq >> 1) + n0) & 3) * 16 + (fq & 1) * 8;
  int c01 = (((fq >> 1) + 2 + n0) & 3) * 16 + (fq & 1) * 8;
  int c10 = (((fq >> 1) + n1) & 3) * 16 + (fq & 1) * 8;
  int c11 = (((fq >> 1) + 2 + n1) & 3) * 16 + (fq & 1) * 8;

  f32x4 acc0 = {0.f, 0.f, 0.f, 0.f}, acc1 = {0.f, 0.f, 0.f, 0.f};
  float sq = 0.f;

  // prologue prefetch (tile 0)
  float4 e = *(const float4*)ep;
  float4 m = *(const float4*)mp;
  uint4 g0 = *(const uint4*)wp;
  uint4 g1 = *(const uint4*)(wp + 8);

#pragma unroll 2
  for (int it = 0; it < 24; ++it) {
    const int buf = it & 1;
    float rx = e.x - m.x, ry = e.y - m.y, rz = e.z - m.z, rw = e.w - m.w;
    sq = fmaf(rx, rx, sq); sq = fmaf(ry, ry, sq);
    sq = fmaf(rz, rz, sq); sq = fmaf(rw, rw, sq);
    uint2 pa;
    pa.x = (unsigned)f2bf(rx) | ((unsigned)f2bf(ry) << 16);
    pa.y = (unsigned)f2bf(rz) | ((unsigned)f2bf(rw) << 16);
    *(uint2*)&As[buf][arow][sA] = pa;
    *(uint4*)&Bs[buf][brow][sB] = g0;
    *(uint4*)&Bs[buf][brow][sB + 8] = g1;
    __syncthreads();
    if (it + 1 < 24) {   // prefetch next tile while MFMA runs
      e = *(const float4*)(ep + (it + 1) * 64);
      m = *(const float4*)(mp + (it + 1) * 64);
      g0 = *(const uint4*)(wp + (it + 1) * 64);
      g1 = *(const uint4*)(wp + (it + 1) * 64 + 8);
    }
    short8 a0 = *(const short8*)&As[buf][ar][cA0];
    short8 a1 = *(const short8*)&As[buf][ar][cA1];
    short8 b00 = *(const short8*)&Bs[buf][n0][c00];
    short8 b01 = *(const short8*)&Bs[buf][n0][c01];
    short8 b10 = *(const short8*)&Bs[buf][n1][c10];
    short8 b11 = *(const short8*)&Bs[buf][n1][c11];
    acc0 = __builtin_amdgcn_mfma_f32_16x16x32_bf16(a0, b00, acc0, 0, 0, 0);
    acc0 = __builtin_amdgcn_mfma_f32_16x16x32_bf16(a1, b01, acc0, 0, 0, 0);
    acc1 = __builtin_amdgcn_mfma_f32_16x16x32_bf16(a0, b10, acc1, 0, 0, 0);
    acc1 = __builtin_amdgcn_mfma_f32_16x16x32_bf16(a1, b11, acc1, 0, 0, 0);
    // no second barrier: next iter writes the other buffer; writes to THIS
    // buffer happen only after the next barrier (safe, see round-3 notes)
  }

  // sumsq: 16 adjacent lanes per row
  sq += __shfl_xor(sq, 1); sq += __shfl_xor(sq, 2);
  sq += __shfl_xor(sq, 4); sq += __shfl_xor(sq, 8);
  if (aseg == 0) atomicAdd(&sumsq[r0 + arow], sq);

  // T accumulate: D layout col=lane&15, row=quad*4+reg
  float* tp = T + (size_t)(r0 + wr * 16 + fq * 4) * 128 + wc * 32 + fr;
#pragma unroll
  for (int ii = 0; ii < 4; ++ii) {
    atomicAdd(tp + (size_t)ii * 128, acc0[ii]);
    atomicAdd(tp + (size_t)ii * 128 + 16, acc1[ii]);
  }
}

// ---------------------------------------------------------------------------
// k_epi: 256 blocks x 32 rows: quad = t^T Minv t; out = scal0 - 0.5*scal1*
//        (sumsq - quad).  (round-2-proven epilogue, T staged from global)
// ---------------------------------------------------------------------------
__global__ __launch_bounds__(256) void k_epi(const float* __restrict__ T,
                                             const float* __restrict__ sumsq,
                                             const float* __restrict__ Minv,
                                             const float* __restrict__ scal,
                                             float* __restrict__ out) {
  __shared__ __align__(16) float Ts[32][132];
  __shared__ float rs[32];
  int t = threadIdx.x;
  int r0 = blockIdx.x * 32;
  int sr = t >> 3, sseg = t & 7;
  const float* tp = T + (size_t)(r0 + sr) * 128 + sseg * 16;
#pragma unroll
  for (int c = 0; c < 4; ++c) {
    float4 v = *(const float4*)(tp + c * 4);
    *(f32x4*)&Ts[sr][sseg * 16 + c * 4] = (f32x4){v.x, v.y, v.z, v.w};
  }
  if (t < 32) rs[t] = sumsq[r0 + t];
  __syncthreads();

  int rp = t >> 4, cg = t & 15;
  int ra = 2 * rp, rb = ra + 1;
  int c0 = cg * 8;
  float ya[8] = {0, 0, 0, 0, 0, 0, 0, 0};
  float yb[8] = {0, 0, 0, 0, 0, 0, 0, 0};
#pragma unroll 4
  for (int j = 0; j < 128; ++j) {
    float tav = Ts[ra][j];
    float tbv = Ts[rb][j];
    float4 v0 = *(const float4*)(Minv + j * LATENT + c0);
    float4 v1 = *(const float4*)(Minv + j * LATENT + c0 + 4);
    ya[0] = fmaf(tav, v0.x, ya[0]); ya[1] = fmaf(tav, v0.y, ya[1]);
    ya[2] = fmaf(tav, v0.z, ya[2]); ya[3] = fmaf(tav, v0.w, ya[3]);
    ya[4] = fmaf(tav, v1.x, ya[4]); ya[5] = fmaf(tav, v1.y, ya[5]);
    ya[6] = fmaf(tav, v1.z, ya[6]); ya[7] = fmaf(tav, v1.w, ya[7]);
    yb[0] = fmaf(tbv, v0.x, yb[0]); yb[1] = fmaf(tbv, v0.y, yb[1]);
    yb[2] = fmaf(tbv, v0.z, yb[2]); yb[3] = fmaf(tbv, v0.w, yb[3]);
    yb[4] = fmaf(tbv, v1.x, yb[4]); yb[5] = fmaf(tbv, v1.y, yb[5]);
    yb[6] = fmaf(tbv, v1.z, yb[6]); yb[7] = fmaf(tbv, v1.w, yb[7]);
  }
  float q0 = 0.f, q1 = 0.f;
#pragma unroll
  for (int c = 0; c < 8; ++c) {
    q0 = fmaf(ya[c], Ts[ra][c0 + c], q0);
    q1 = fmaf(yb[c], Ts[rb][c0 + c], q1);
  }
  q0 += __shfl_xor(q0, 1); q0 += __shfl_xor(q0, 2);
  q0 += __shfl_xor(q0, 4); q0 += __shfl_xor(q0, 8);
  q1 += __shfl_xor(q1, 1); q1 += __shfl_xor(q1, 2);
  q1 += __shfl_xor(q1, 4); q1 += __shfl_xor(q1, 8);
  if (cg == 0) {
    float cc = scal[0], is2 = scal[1];
    out[r0 + ra] = cc - 0.5f * is2 * (rs[ra] - q0);
    out[r0 + rb] = cc - 0.5f * is2 * (rs[rb] - q1);
  }
}

// ---------------------------------------------------------------------------
extern "C" void kernel_launch(void* const* d_in, const int* in_sizes, int n_in,
                              void* d_out, int out_size, void* d_ws, size_t ws_size,
                              hipStream_t stream) {
  (void)in_sizes; (void)n_in; (void)out_size; (void)ws_size;
  const float* ex   = (const float*)d_in[0];
  const float* W    = (const float*)d_in[1];
  const float* lv   = (const float*)d_in[2];
  const float* mean = (const float*)d_in[3];
  float* out = (float*)d_out;

  // ws: M(16384f) | scal(64f) | T(1048576f) | sumsq(8192f) | Wt(393216 bf16)
  float* M = (float*)d_ws;
  float* scal = M + 16384;
  float* T = scal + 64;
  float* sumsq = T + 1048576;
  unsigned short* Wt = (unsigned short*)(sumsq + 8192);

  hipMemsetAsync(M, 0, (size_t)(16384 + 64 + 1048576 + 8192) * sizeof(float),
                 stream);
  k_prep<<<48, 256, 0, stream>>>(W, M, Wt);
  k_gemm<<<GB + 1, 512, 0, stream>>>(ex, mean, Wt, M, scal, lv, T, sumsq);
  k_epi<<<256, 256, 0, stream>>>(T, sumsq, M, scal, out);
}